// Round 14
// baseline (337.124 us; speedup 1.0000x reference)
//
#include <hip/hip_runtime.h>
#include <hip/hip_bf16.h>
#include <cstdint>
#include <cstddef>

// Round 14: attn_fused QBLK 16 -> 32 rows (1024 thr, 16 waves, 148 KB LDS,
// 1 block/CU). Halves total K/V L2 read traffic (2 GB -> 1 GB). All MFMA
// fragment layouts / swizzles / mask decomposition inherited from r12.
// ph4 = pure PV; attn NT stores as tail (r13 style, proven neutral).

typedef __attribute__((ext_vector_type(8)))  short short8v;
typedef __attribute__((ext_vector_type(2)))  float f32x2;
typedef __attribute__((ext_vector_type(4)))  float f32x4;
typedef __attribute__((ext_vector_type(16))) float f32x16;

constexpr int DM = 512, S = 2048, BATCH = 4, NHEAD = 8, DK = 64;
constexpr int ROWS = BATCH * S;                 // 8192
constexpr int BH   = BATCH * NHEAD;             // 32
constexpr size_t OUT_ELEMS = (size_t)ROWS * DM; // 4,194,304
constexpr size_t HFRAG = 131072;                // elems per bh in packed k/v

#define ZERO16 {0.f,0.f,0.f,0.f,0.f,0.f,0.f,0.f,0.f,0.f,0.f,0.f,0.f,0.f,0.f,0.f}

__device__ __forceinline__ unsigned short f2bf(float f) {
    union { __hip_bfloat16 b; unsigned short u; } c;
    c.b = __float2bfloat16(f);   // RNE
    return c.u;
}
__device__ __forceinline__ float bf2f(unsigned short u) {
    union { float f; unsigned u32; } c;
    c.u32 = (unsigned)u << 16;
    return c.f;
}

// ---------------------------------------------------------------------------
__global__ __launch_bounds__(256)
void wconv(const float* __restrict__ Wq, const float* __restrict__ Wk,
           const float* __restrict__ Wv, const float* __restrict__ Wo,
           unsigned short* __restrict__ wt)
{
    __shared__ float T[32][33];
    const float* srcs[4] = {Wq, Wk, Wv, Wo};
    const float* W = srcs[blockIdx.z];
    unsigned short* out = wt + (size_t)blockIdx.z * DM * DM;
    const int r0 = blockIdx.y * 32, c0 = blockIdx.x * 32;
    const int tid = threadIdx.x;
#pragma unroll
    for (int i = 0; i < 4; ++i) {
        int lin = tid + i * 256; int r = lin >> 5, c = lin & 31;
        T[r][c] = W[(size_t)(r0 + r) * DM + c0 + c];
    }
    __syncthreads();
#pragma unroll
    for (int i = 0; i < 4; ++i) {
        int lin = tid + i * 256; int rn = lin >> 5, ck = lin & 31;
        out[(size_t)(c0 + rn) * DM + r0 + ck] = f2bf(T[ck][rn]);
    }
}

// ---------------------------------------------------------------------------
// Pack bool mask to bits: mb[row][w] bit k <-> mask[row][32w+k]!=0.
__global__ __launch_bounds__(256)
void maskpack(const uint8_t* __restrict__ mask, unsigned* __restrict__ mb)
{
    const int t = threadIdx.x;
    const int row = blockIdx.x * 4 + (t >> 6);
    const int w = t & 63;
    const uint8_t* src = mask + (size_t)row * S + 32 * w;
    const uint4 a = *reinterpret_cast<const uint4*>(src);
    const uint4 b = *reinterpret_cast<const uint4*>(src + 16);
    const unsigned m8[8] = {a.x, a.y, a.z, a.w, b.x, b.y, b.z, b.w};
    unsigned bits = 0;
#pragma unroll
    for (int k2 = 0; k2 < 32; ++k2)
        bits |= (((m8[k2 >> 2] >> (8 * (k2 & 3))) & 0xffu) ? 1u : 0u) << k2;
    mb[(size_t)row * 64 + w] = bits;
}

// ---------------------------------------------------------------------------
// Projections. q: [bh][s][64]. k/v in fragment-packed layouts (round 4).
// Epilogue: LDS-staged coalesced stores (z=0/1), ushort4 direct (z=2).
__global__ __launch_bounds__(256)
void proj3_mfma(const float* __restrict__ Qin, const float* __restrict__ Kin,
                const float* __restrict__ Vin, const unsigned short* __restrict__ wt,
                const float* __restrict__ bq, const float* __restrict__ bk,
                const float* __restrict__ bv,
                unsigned short* __restrict__ qo, unsigned short* __restrict__ ko,
                unsigned short* __restrict__ vo)
{
    __shared__ __align__(16) char stg[16384];   // 4 waves x 4KB, wave-private
    const int z = blockIdx.z;
    const float* X = (z == 0) ? Qin : (z == 1) ? Kin : Vin;
    const unsigned short* Wt = wt + (size_t)z * DM * DM;
    const float* bias = (z == 0) ? bq : (z == 1) ? bk : bv;
    const float scale = (z == 0) ? 0.125f : 1.0f;

    const int tid = threadIdx.x, wv = tid >> 6, l = tid & 63, lr = l & 31, lh = l >> 5;
    const int m0 = blockIdx.y * 128 + wv * 32;
    const int n0 = blockIdx.x * 64;
    const float* xp = X + (size_t)(m0 + lr) * DM + 8 * lh;
    const unsigned short* w0 = Wt + (size_t)(n0 + lr) * DM + 8 * lh;
    const unsigned short* w1 = w0 + (size_t)32 * DM;
    f32x16 acc0 = ZERO16, acc1 = ZERO16;
#pragma unroll 8
    for (int t = 0; t < 32; ++t) {
        float4 xa = *reinterpret_cast<const float4*>(xp + 16 * t);
        float4 xb = *reinterpret_cast<const float4*>(xp + 16 * t + 4);
        short8v a;
        a[0] = (short)f2bf(xa.x * scale); a[1] = (short)f2bf(xa.y * scale);
        a[2] = (short)f2bf(xa.z * scale); a[3] = (short)f2bf(xa.w * scale);
        a[4] = (short)f2bf(xb.x * scale); a[5] = (short)f2bf(xb.y * scale);
        a[6] = (short)f2bf(xb.z * scale); a[7] = (short)f2bf(xb.w * scale);
        short8v b0 = *reinterpret_cast<const short8v*>(w0 + 16 * t);
        short8v b1 = *reinterpret_cast<const short8v*>(w1 + 16 * t);
        acc0 = __builtin_amdgcn_mfma_f32_32x32x16_bf16(a, b0, acc0, 0, 0, 0);
        acc1 = __builtin_amdgcn_mfma_f32_32x32x16_bf16(a, b1, acc1, 0, 0, 0);
    }

    const int h  = n0 >> 6;
    const int b  = m0 >> 11;
    const int bh = b * NHEAD + h;
    const float bv0 = bias[n0 + lr] * scale;
    const float bv1 = bias[n0 + 32 + lr] * scale;

    if (z == 2) {
        const int s32 = (m0 & (S - 1)) >> 5;
        unsigned short* vp = vo + (size_t)bh * HFRAG + (size_t)s32 * 2048;
#pragma unroll
        for (int j = 0; j < 2; ++j) {
            const f32x16 acc = j ? acc1 : acc0;
            const float bvv = j ? bv1 : bv0;
            const int d = 32 * j + lr;
            const size_t dbase = (size_t)(d >> 4) * 512;
#pragma unroll
            for (int rq = 0; rq < 4; ++rq) {
                ushort4 pk;
                pk.x = f2bf(acc[rq * 4 + 0] + bvv);
                pk.y = f2bf(acc[rq * 4 + 1] + bvv);
                pk.z = f2bf(acc[rq * 4 + 2] + bvv);
                pk.w = f2bf(acc[rq * 4 + 3] + bvv);
                const size_t idx = dbase + (size_t)(((d & 15) + 16 * rq) << 3) + 4 * lh;
                *reinterpret_cast<ushort4*>(vp + idx) = pk;
            }
        }
    } else {
        char* tb = stg + wv * 4096;
#pragma unroll
        for (int j = 0; j < 2; ++j) {
            const f32x16 acc = j ? acc1 : acc0;
            const float bvv = j ? bv1 : bv0;
            const int cb = (32 * j + lr) * 2;
#pragma unroll
            for (int r = 0; r < 16; ++r) {
                const int ml = (r & 3) + 8 * (r >> 2) + 4 * lh;
                *reinterpret_cast<unsigned short*>(
                    tb + ml * 128 + (cb ^ ((ml & 7) << 4))) = f2bf(acc[r] + bvv);
            }
        }
        if (z == 0) {
            const int s0 = m0 & (S - 1);
            unsigned short* qp = qo + ((size_t)bh * S + s0) * DK;
#pragma unroll
            for (int it = 0; it < 4; ++it) {
                const int row = it * 8 + (l >> 3);
                const int cb = (l & 7) * 16;
                const short8v v = *reinterpret_cast<const short8v*>(
                    tb + row * 128 + (cb ^ ((row & 7) << 4)));
                *reinterpret_cast<short8v*>(
                    reinterpret_cast<char*>(qp + (size_t)row * DK) + cb) = v;
            }
        } else {
            const int s16 = (m0 & (S - 1)) >> 4;
            unsigned short* kp = ko + (size_t)bh * HFRAG + (size_t)s16 * 1024;
#pragma unroll
            for (int it = 0; it < 4; ++it) {
                const int sb = it >> 1, dh = it & 1;
                const int srow = sb * 16 + (l & 15);
                const int dg = l >> 4;
                const short8v v = *reinterpret_cast<const short8v*>(
                    tb + srow * 128 + ((dh * 64 + dg * 16) ^ ((srow & 7) << 4)));
                *reinterpret_cast<short8v*>(
                    kp + (size_t)sb * 1024 + dh * 512 + l * 8) = v;
            }
        }
    }
}

// ---------------------------------------------------------------------------
// Fused attention, 32 q-rows per block, 16 waves. bid: xcd = bid&7,
// bhl = (bid>>3)&3, tile = bid>>5; bh = 4*xcd+bhl, q0 = tile*32.
// QK^T: wave wv owns cols [128wv,128wv+128), lane's rows = lq and 16+lq.
// PV waves: rt = wv&1 (row-tile), dt = (wv>>1)&3 (d-tile), kh = wv>>3.
__global__ __launch_bounds__(1024, 4)
void attn_fused(const unsigned short* __restrict__ q,
                const unsigned short* __restrict__ kpack,
                const unsigned short* __restrict__ vpack,
                const unsigned* __restrict__ mbits,
                float* __restrict__ attn,
                unsigned short* __restrict__ ctx)
{
    __shared__ char Pc[32 * 4096];            // 128 KB: 32 rows x 2048 bf16
    __shared__ float cred[2][2][4][16][16];   // 16 KB [kh][rt][dt][row][col]
    __shared__ float redm[16][32];            // per-wave row max (32 rows)
    __shared__ float reds[16][32];            // per-wave row sum
    const int tid = threadIdx.x, wv = tid >> 6, l = tid & 63;
    const int lq = l & 15, lg = l >> 4;
    const int bid = blockIdx.x;
    const int bh = 4 * (bid & 7) + ((bid >> 3) & 3);
    const int q0 = (bid >> 5) * 32;
    const int b = bh >> 3, h = bh & 7;

    // ---- Phase 1: QK^T swapped, two row-groups (rows lq and 16+lq).
    const unsigned short* qpa = q + ((size_t)bh * S + q0 + lq) * DK + 8 * lg;
    const unsigned short* qpb = qpa + (size_t)16 * DK;
    const short8v qa0 = *reinterpret_cast<const short8v*>(qpa);
    const short8v qa1 = *reinterpret_cast<const short8v*>(qpa + 32);
    const short8v qb0 = *reinterpret_cast<const short8v*>(qpb);
    const short8v qb1 = *reinterpret_cast<const short8v*>(qpb + 32);
    const unsigned short* kbase = kpack + (size_t)bh * HFRAG + (size_t)l * 8;
    f32x4 accA[8], accB[8];
#pragma unroll
    for (int it = 0; it < 8; ++it) {
        const unsigned short* kc = kbase + (size_t)(8 * wv + it) * 1024;
        const short8v kf0 = *reinterpret_cast<const short8v*>(kc);
        const short8v kf1 = *reinterpret_cast<const short8v*>(kc + 512);
        f32x4 a = {0.f, 0.f, 0.f, 0.f};
        a = __builtin_amdgcn_mfma_f32_16x16x32_bf16(kf0, qa0, a, 0, 0, 0);
        a = __builtin_amdgcn_mfma_f32_16x16x32_bf16(kf1, qa1, a, 0, 0, 0);
        accA[it] = a;
        f32x4 bb = {0.f, 0.f, 0.f, 0.f};
        bb = __builtin_amdgcn_mfma_f32_16x16x32_bf16(kf0, qb0, bb, 0, 0, 0);
        bb = __builtin_amdgcn_mfma_f32_16x16x32_bf16(kf1, qb1, bb, 0, 0, 0);
        accB[it] = bb;
    }

    // ---- Phase 2: mask + row max/sum for both row-groups.
    // cols [128wv,128wv+128) -> mask words 4wv..4wv+3 of each row.
    const unsigned* mra = mbits + ((size_t)b * S + q0 + lq) * 64 + 4 * wv;
    const unsigned* mrb = mra + (size_t)16 * 64;
    const uint4 m4a = *reinterpret_cast<const uint4*>(mra);
    const uint4 m4b = *reinterpret_cast<const uint4*>(mrb);
    const unsigned mwA[4] = {m4a.x, m4a.y, m4a.z, m4a.w};
    const unsigned mwB[4] = {m4b.x, m4b.y, m4b.z, m4b.w};
    float vmaxA = -3e38f, vmaxB = -3e38f;
#pragma unroll
    for (int it = 0; it < 8; ++it) {
        const int sh = 16 * (it & 1) + 4 * lg;
        const unsigned wa = mwA[it >> 1] >> sh;
        const unsigned wb = mwB[it >> 1] >> sh;
#pragma unroll
        for (int r = 0; r < 4; ++r) {
            const float va = ((wa >> r) & 1u) ? -1e30f : accA[it][r];
            accA[it][r] = va; vmaxA = fmaxf(vmaxA, va);
            const float vb = ((wb >> r) & 1u) ? -1e30f : accB[it][r];
            accB[it][r] = vb; vmaxB = fmaxf(vmaxB, vb);
        }
    }
    vmaxA = fmaxf(vmaxA, __shfl_xor(vmaxA, 16));
    vmaxA = fmaxf(vmaxA, __shfl_xor(vmaxA, 32));
    vmaxB = fmaxf(vmaxB, __shfl_xor(vmaxB, 16));
    vmaxB = fmaxf(vmaxB, __shfl_xor(vmaxB, 32));
    if (l < 16) { redm[wv][l] = vmaxA; redm[wv][16 + l] = vmaxB; }
    __syncthreads();
    float rmaxA = redm[0][lq], rmaxB = redm[0][16 + lq];
#pragma unroll
    for (int w2 = 1; w2 < 16; ++w2) {
        rmaxA = fmaxf(rmaxA, redm[w2][lq]);
        rmaxB = fmaxf(rmaxB, redm[w2][16 + lq]);
    }

    float sumA = 0.f, sumB = 0.f;
#pragma unroll
    for (int it = 0; it < 8; ++it)
#pragma unroll
        for (int r = 0; r < 4; ++r) {
            const float va = __expf(accA[it][r] - rmaxA);
            accA[it][r] = va; sumA += va;
            const float vb = __expf(accB[it][r] - rmaxB);
            accB[it][r] = vb; sumB += vb;
        }
    sumA += __shfl_xor(sumA, 16);
    sumA += __shfl_xor(sumA, 32);
    sumB += __shfl_xor(sumB, 16);
    sumB += __shfl_xor(sumB, 32);
    if (l < 16) { reds[wv][l] = sumA; reds[wv][16 + l] = sumB; }
    __syncthreads();
    float rsumA = 0.f, rsumB = 0.f;
#pragma unroll
    for (int w2 = 0; w2 < 16; ++w2) {
        rsumA += reds[w2][lq];
        rsumB += reds[w2][16 + lq];
    }
    const float invA = 1.0f / rsumA, invB = 1.0f / rsumB;

    // ---- Phase 3: normalize in regs; P bf16 -> LDS (rows lq and 16+lq).
    const int swz = (lq & 7) << 4;     // (16+lq)&7 == lq&7 -> same swizzle
    char* prowA = Pc + lq * 4096;
    char* prowB = Pc + (16 + lq) * 4096;
#pragma unroll
    for (int it = 0; it < 8; ++it) {
        const int n = 128 * wv + 16 * it + 4 * lg;
        ushort4 pa, pb;
        pa.x = f2bf(accA[it][0] * invA); pa.y = f2bf(accA[it][1] * invA);
        pa.z = f2bf(accA[it][2] * invA); pa.w = f2bf(accA[it][3] * invA);
        pb.x = f2bf(accB[it][0] * invB); pb.y = f2bf(accB[it][1] * invB);
        pb.z = f2bf(accB[it][2] * invB); pb.w = f2bf(accB[it][3] * invB);
        *reinterpret_cast<ushort4*>(prowA + ((2 * n) ^ swz)) = pa;
        *reinterpret_cast<ushort4*>(prowB + ((2 * n) ^ swz)) = pb;
    }
    __syncthreads();

    // ---- Phase 4: pure PV MFMA. rt = wv&1, dt = (wv>>1)&3, kh = wv>>3.
    const int rt = wv & 1, dt = (wv >> 1) & 3, kh = wv >> 3;
    const int rswz = (lq & 7) << 4;
    f32x4 pacc = {0.f, 0.f, 0.f, 0.f};
    const unsigned short* vbase = vpack + (size_t)bh * HFRAG + dt * 512 + (size_t)l * 8;
    const char* prow = Pc + (16 * rt + lq) * 4096;
#pragma unroll 8
    for (int s = 0; s < 32; ++s) {
        const int kk0 = kh * 1024 + 32 * s;
        const short8v a = *reinterpret_cast<const short8v*>(
            prow + ((2 * (kk0 + 8 * lg)) ^ rswz));
        const short8v bf = *reinterpret_cast<const short8v*>(
            vbase + (size_t)(kh * 32 + s) * 2048);
        pacc = __builtin_amdgcn_mfma_f32_16x16x32_bf16(a, bf, pacc, 0, 0, 0);
    }
#pragma unroll
    for (int r = 0; r < 4; ++r) cred[kh][rt][dt][lg * 4 + r][lq] = pacc[r];
    __syncthreads();

    // ---- ctx write (32 rows x 64 d)
    for (int o = tid; o < 2048; o += 1024) {
        const int qq = o >> 6, dd = o & 63;
        const float val = cred[0][qq >> 4][dd >> 4][qq & 15][dd & 15]
                        + cred[1][qq >> 4][dd >> 4][qq & 15][dd & 15];
        ctx[((size_t)(b * S + q0 + qq)) * DM + h * DK + dd] = f2bf(val);
    }

    // ---- Tail: attn NT stores (f32x4 from LDS), nothing after them.
    const int srow = 2 * wv + (l >> 5);                 // 0..31
    const int sswz = (srow & 7) << 4;
    const int lc = l & 31;
    float* arow = attn + ((size_t)bh * S + q0 + srow) * S;
#pragma unroll
    for (int s5 = 0; s5 < 16; ++s5) {
        const ushort4 pw = *reinterpret_cast<const ushort4*>(
            Pc + srow * 4096 + ((8 * lc + 256 * s5) ^ sswz));
        f32x4 st;
        st[0] = bf2f(pw.x); st[1] = bf2f(pw.y);
        st[2] = bf2f(pw.z); st[3] = bf2f(pw.w);
        __builtin_nontemporal_store(st,
            reinterpret_cast<f32x4*>(arow + 4 * lc + 128 * s5));
    }
}

// ---------------------------------------------------------------------------
// Fused output projection + residual + LayerNorm.
__global__ __launch_bounds__(512)
void out_ln(const unsigned short* __restrict__ Xc, const unsigned short* __restrict__ Wt,
            const float* __restrict__ bias, const float* __restrict__ resid,
            float* __restrict__ out)
{
    __shared__ f32x2 red[32][8];
    __shared__ f32x2 stat[32];
    const int tid = threadIdx.x, wv = tid >> 6, l = tid & 63, lr = l & 31, lh = l >> 5;
    const int m0 = blockIdx.x * 32;
    const int n0 = wv * 64;
    const unsigned short* xp = Xc + (size_t)(m0 + lr) * DM + 8 * lh;
    const unsigned short* w0 = Wt + (size_t)(n0 + lr) * DM + 8 * lh;
    const unsigned short* w1 = w0 + (size_t)32 * DM;
    f32x16 acc0 = ZERO16, acc1 = ZERO16;
#pragma unroll 8
    for (int t = 0; t < 32; ++t) {
        short8v a  = *reinterpret_cast<const short8v*>(xp + 16 * t);
        short8v b0 = *reinterpret_cast<const short8v*>(w0 + 16 * t);
        short8v b1 = *reinterpret_cast<const short8v*>(w1 + 16 * t);
        acc0 = __builtin_amdgcn_mfma_f32_32x32x16_bf16(a, b0, acc0, 0, 0, 0);
        acc1 = __builtin_amdgcn_mfma_f32_32x32x16_bf16(a, b1, acc1, 0, 0, 0);
    }
    const float bv0 = bias[n0 + lr], bv1 = bias[n0 + 32 + lr];
#pragma unroll
    for (int r = 0; r < 16; ++r) {
        const int mloc = (r & 3) + 8 * (r >> 2) + 4 * lh;
        const size_t mbase = (size_t)(m0 + mloc) * DM + n0 + lr;
        const float v0 = acc0[r] + bv0 + resid[mbase];
        const float v1 = acc1[r] + bv1 + resid[mbase + 32];
        acc0[r] = v0; acc1[r] = v1;
        float s = v0 + v1, sq = v0 * v0 + v1 * v1;
#pragma unroll
        for (int off = 16; off; off >>= 1) {
            s  += __shfl_xor(s, off);
            sq += __shfl_xor(sq, off);
        }
        if (lr == 0) { f32x2 t2; t2[0] = s; t2[1] = sq; red[mloc][wv] = t2; }
    }
    __syncthreads();
    if (tid < 32) {
        float s = 0.f, sq = 0.f;
#pragma unroll
        for (int w2 = 0; w2 < 8; ++w2) { s += red[tid][w2][0]; sq += red[tid][w2][1]; }
        const float mean = s * (1.0f / 512.0f);
        const float var = sq * (1.0f / 512.0f) - mean * mean;
        f32x2 t2; t2[0] = mean; t2[1] = rsqrtf(var + 1e-5f);
        stat[tid] = t2;
    }
    __syncthreads();
#pragma unroll
    for (int r = 0; r < 16; ++r) {
        const int mloc = (r & 3) + 8 * (r >> 2) + 4 * lh;
        const f32x2 st = stat[mloc];
        const size_t mbase = (size_t)(m0 + mloc) * DM + n0 + lr;
        out[mbase]      = (acc0[r] - st[0]) * st[1];
        out[mbase + 32] = (acc1[r] - st[0]) * st[1];
    }
}

// ---------------------------------------------------------------------------
extern "C" void kernel_launch(void* const* d_in, const int* in_sizes, int n_in,
                              void* d_out, int out_size, void* d_ws, size_t ws_size,
                              hipStream_t stream)
{
    (void)in_sizes; (void)n_in; (void)out_size; (void)ws_size;

    const float*   Qin  = (const float*)d_in[0];
    const float*   Kin  = (const float*)d_in[1];
    const float*   Vin  = (const float*)d_in[2];
    const uint8_t* mask = (const uint8_t*)d_in[3];
    const float*   Wq   = (const float*)d_in[4];
    const float*   bq   = (const float*)d_in[5];
    const float*   Wk   = (const float*)d_in[6];
    const float*   bk   = (const float*)d_in[7];
    const float*   Wv   = (const float*)d_in[8];
    const float*   bv   = (const float*)d_in[9];
    const float*   Wo   = (const float*)d_in[10];
    const float*   bo   = (const float*)d_in[11];

    float* out  = (float*)d_out;
    float* attn = out + OUT_ELEMS;

    char* w = (char*)d_ws;
    const size_t MB = 1 << 20;
    unsigned short* wt    = (unsigned short*)(w);             // 2 MB (4 matrices)
    unsigned short* qbf   = (unsigned short*)(w + 2  * MB);   // 8 MB
    unsigned short* kpack = (unsigned short*)(w + 10 * MB);   // 8 MB
    unsigned short* vpack = (unsigned short*)(w + 18 * MB);   // 8 MB
    unsigned short* ctx   = (unsigned short*)(w + 26 * MB);   // 8 MB
    unsigned*       mbits = (unsigned*)(w + 34 * MB);         // 2 MB -> 36 MB

    unsigned short* wto = wt + 3 * (size_t)DM * DM;

    wconv<<<dim3(16, 16, 4), 256, 0, stream>>>(Wq, Wk, Wv, Wo, wt);

    maskpack<<<ROWS / 4, 256, 0, stream>>>(mask, mbits);

    proj3_mfma<<<dim3(DM / 64, ROWS / 128, 3), 256, 0, stream>>>(
        Qin, Kin, Vin, wt, bq, bk, bv, qbf, kpack, vpack);

    attn_fused<<<2048, 1024, 0, stream>>>(qbf, kpack, vpack, mbits, attn, ctx);

    out_ln<<<ROWS / 32, 512, 0, stream>>>(ctx, wto, bo, Qin, out);
}

// Round 15
// 316.080 us; speedup vs baseline: 1.0666x; 1.0666x over previous
//
#include <hip/hip_runtime.h>
#include <hip/hip_bf16.h>
#include <cstdint>
#include <cstddef>
#include <math.h>

// Round 15: r12 (best, 309us) + (1) exp2 fold: q pre-scaled by 0.125*log2e,
// softmax uses native exp2f (saves one v_mul per score element);
// (2) maskpack merged into proj3's grid as z=3 (one fewer launch).
// All layouts / swizzles / store paths byte-identical to r12.

typedef __attribute__((ext_vector_type(8)))  short short8v;
typedef __attribute__((ext_vector_type(2)))  float f32x2;
typedef __attribute__((ext_vector_type(4)))  float f32x4;
typedef __attribute__((ext_vector_type(16))) float f32x16;

constexpr int DM = 512, S = 2048, BATCH = 4, NHEAD = 8, DK = 64;
constexpr int ROWS = BATCH * S;                 // 8192
constexpr int BH   = BATCH * NHEAD;             // 32
constexpr size_t OUT_ELEMS = (size_t)ROWS * DM; // 4,194,304
constexpr size_t HFRAG = 131072;                // elems per bh in packed k/v
constexpr float QSCALE = 0.125f * 1.4426950408889634f;  // 1/8 * log2(e)

#define ZERO16 {0.f,0.f,0.f,0.f,0.f,0.f,0.f,0.f,0.f,0.f,0.f,0.f,0.f,0.f,0.f,0.f}

__device__ __forceinline__ unsigned short f2bf(float f) {
    union { __hip_bfloat16 b; unsigned short u; } c;
    c.b = __float2bfloat16(f);   // RNE
    return c.u;
}
__device__ __forceinline__ float bf2f(unsigned short u) {
    union { float f; unsigned u32; } c;
    c.u32 = (unsigned)u << 16;
    return c.f;
}

// ---------------------------------------------------------------------------
__global__ __launch_bounds__(256)
void wconv(const float* __restrict__ Wq, const float* __restrict__ Wk,
           const float* __restrict__ Wv, const float* __restrict__ Wo,
           unsigned short* __restrict__ wt)
{
    __shared__ float T[32][33];
    const float* srcs[4] = {Wq, Wk, Wv, Wo};
    const float* W = srcs[blockIdx.z];
    unsigned short* out = wt + (size_t)blockIdx.z * DM * DM;
    const int r0 = blockIdx.y * 32, c0 = blockIdx.x * 32;
    const int tid = threadIdx.x;
#pragma unroll
    for (int i = 0; i < 4; ++i) {
        int lin = tid + i * 256; int r = lin >> 5, c = lin & 31;
        T[r][c] = W[(size_t)(r0 + r) * DM + c0 + c];
    }
    __syncthreads();
#pragma unroll
    for (int i = 0; i < 4; ++i) {
        int lin = tid + i * 256; int rn = lin >> 5, ck = lin & 31;
        out[(size_t)(c0 + rn) * DM + r0 + ck] = f2bf(T[ck][rn]);
    }
}

// ---------------------------------------------------------------------------
// Projections (z=0/1/2) + mask bit-pack (z=3).
// q: [bh][s][64] pre-scaled by QSCALE. k/v in fragment-packed layouts.
__global__ __launch_bounds__(256)
void proj3_mfma(const float* __restrict__ Qin, const float* __restrict__ Kin,
                const float* __restrict__ Vin, const unsigned short* __restrict__ wt,
                const float* __restrict__ bq, const float* __restrict__ bk,
                const float* __restrict__ bv,
                const uint8_t* __restrict__ mask, unsigned* __restrict__ mb,
                unsigned short* __restrict__ qo, unsigned short* __restrict__ ko,
                unsigned short* __restrict__ vo)
{
    __shared__ __align__(16) char stg[16384];   // 4 waves x 4KB, wave-private
    const int z = blockIdx.z;
    const int tid = threadIdx.x;

    if (z == 3) {
        // maskpack: 512 blocks (y*8+x), 16 rows/block, 4 u32 words/thread.
        const int bid = blockIdx.y * 8 + blockIdx.x;
        const int row = bid * 16 + (tid >> 4);
        const int w0i = (tid & 15) * 4;
        const uint8_t* src = mask + (size_t)row * S + 32 * w0i;
        uint4 outw;
        unsigned* ow = reinterpret_cast<unsigned*>(&outw);
#pragma unroll
        for (int wi = 0; wi < 4; ++wi) {
            const uint4 a = *reinterpret_cast<const uint4*>(src + 32 * wi);
            const uint4 bquad = *reinterpret_cast<const uint4*>(src + 32 * wi + 16);
            const unsigned m8[8] = {a.x, a.y, a.z, a.w,
                                    bquad.x, bquad.y, bquad.z, bquad.w};
            unsigned bits = 0;
#pragma unroll
            for (int k2 = 0; k2 < 32; ++k2)
                bits |= (((m8[k2 >> 2] >> (8 * (k2 & 3))) & 0xffu) ? 1u : 0u) << k2;
            ow[wi] = bits;
        }
        *reinterpret_cast<uint4*>(mb + (size_t)row * 64 + w0i) = outw;
        return;
    }

    const float* X = (z == 0) ? Qin : (z == 1) ? Kin : Vin;
    const unsigned short* Wt = wt + (size_t)z * DM * DM;
    const float* bias = (z == 0) ? bq : (z == 1) ? bk : bv;
    const float scale = (z == 0) ? QSCALE : 1.0f;

    const int wv = tid >> 6, l = tid & 63, lr = l & 31, lh = l >> 5;
    const int m0 = blockIdx.y * 128 + wv * 32;
    const int n0 = blockIdx.x * 64;
    const float* xp = X + (size_t)(m0 + lr) * DM + 8 * lh;
    const unsigned short* w0 = Wt + (size_t)(n0 + lr) * DM + 8 * lh;
    const unsigned short* w1 = w0 + (size_t)32 * DM;
    f32x16 acc0 = ZERO16, acc1 = ZERO16;
#pragma unroll 8
    for (int t = 0; t < 32; ++t) {
        float4 xa = *reinterpret_cast<const float4*>(xp + 16 * t);
        float4 xb = *reinterpret_cast<const float4*>(xp + 16 * t + 4);
        short8v a;
        a[0] = (short)f2bf(xa.x * scale); a[1] = (short)f2bf(xa.y * scale);
        a[2] = (short)f2bf(xa.z * scale); a[3] = (short)f2bf(xa.w * scale);
        a[4] = (short)f2bf(xb.x * scale); a[5] = (short)f2bf(xb.y * scale);
        a[6] = (short)f2bf(xb.z * scale); a[7] = (short)f2bf(xb.w * scale);
        short8v b0 = *reinterpret_cast<const short8v*>(w0 + 16 * t);
        short8v b1 = *reinterpret_cast<const short8v*>(w1 + 16 * t);
        acc0 = __builtin_amdgcn_mfma_f32_32x32x16_bf16(a, b0, acc0, 0, 0, 0);
        acc1 = __builtin_amdgcn_mfma_f32_32x32x16_bf16(a, b1, acc1, 0, 0, 0);
    }

    const int h  = n0 >> 6;
    const int b  = m0 >> 11;
    const int bh = b * NHEAD + h;
    const float bv0 = bias[n0 + lr] * scale;
    const float bv1 = bias[n0 + 32 + lr] * scale;

    if (z == 2) {
        const int s32 = (m0 & (S - 1)) >> 5;
        unsigned short* vp = vo + (size_t)bh * HFRAG + (size_t)s32 * 2048;
#pragma unroll
        for (int j = 0; j < 2; ++j) {
            const f32x16 acc = j ? acc1 : acc0;
            const float bvv = j ? bv1 : bv0;
            const int d = 32 * j + lr;
            const size_t dbase = (size_t)(d >> 4) * 512;
#pragma unroll
            for (int rq = 0; rq < 4; ++rq) {
                ushort4 pk;
                pk.x = f2bf(acc[rq * 4 + 0] + bvv);
                pk.y = f2bf(acc[rq * 4 + 1] + bvv);
                pk.z = f2bf(acc[rq * 4 + 2] + bvv);
                pk.w = f2bf(acc[rq * 4 + 3] + bvv);
                const size_t idx = dbase + (size_t)(((d & 15) + 16 * rq) << 3) + 4 * lh;
                *reinterpret_cast<ushort4*>(vp + idx) = pk;
            }
        }
    } else {
        char* tb = stg + wv * 4096;
#pragma unroll
        for (int j = 0; j < 2; ++j) {
            const f32x16 acc = j ? acc1 : acc0;
            const float bvv = j ? bv1 : bv0;
            const int cb = (32 * j + lr) * 2;
#pragma unroll
            for (int r = 0; r < 16; ++r) {
                const int ml = (r & 3) + 8 * (r >> 2) + 4 * lh;
                *reinterpret_cast<unsigned short*>(
                    tb + ml * 128 + (cb ^ ((ml & 7) << 4))) = f2bf(acc[r] + bvv);
            }
        }
        if (z == 0) {
            const int s0 = m0 & (S - 1);
            unsigned short* qp = qo + ((size_t)bh * S + s0) * DK;
#pragma unroll
            for (int it = 0; it < 4; ++it) {
                const int row = it * 8 + (l >> 3);
                const int cb = (l & 7) * 16;
                const short8v v = *reinterpret_cast<const short8v*>(
                    tb + row * 128 + (cb ^ ((row & 7) << 4)));
                *reinterpret_cast<short8v*>(
                    reinterpret_cast<char*>(qp + (size_t)row * DK) + cb) = v;
            }
        } else {
            const int s16 = (m0 & (S - 1)) >> 4;
            unsigned short* kp = ko + (size_t)bh * HFRAG + (size_t)s16 * 1024;
#pragma unroll
            for (int it = 0; it < 4; ++it) {
                const int sb = it >> 1, dh = it & 1;
                const int srow = sb * 16 + (l & 15);
                const int dg = l >> 4;
                const short8v v = *reinterpret_cast<const short8v*>(
                    tb + srow * 128 + ((dh * 64 + dg * 16) ^ ((srow & 7) << 4)));
                *reinterpret_cast<short8v*>(
                    kp + (size_t)sb * 1024 + dh * 512 + l * 8) = v;
            }
        }
    }
}

// ---------------------------------------------------------------------------
// Fused attention (r12 structure, exp2 softmax). XCD-aware bid decomposition:
// xcd = bid&7, bhl = (bid>>3)&3, tile = bid>>5; bh = 4*xcd+bhl, q0 = tile*16.
__global__ __launch_bounds__(512, 4)
void attn_fused(const unsigned short* __restrict__ q,
                const unsigned short* __restrict__ kpack,
                const unsigned short* __restrict__ vpack,
                const unsigned* __restrict__ mbits,
                float* __restrict__ attn,
                unsigned short* __restrict__ ctx)
{
    __shared__ char Pc[16 * 4096];        // 64 KB: 16 rows x 2048 bf16, swizzled
    __shared__ float cred[2][4][16][16];  // 8 KB PV cross-wave reduce
    __shared__ float redm[8][16];
    __shared__ float reds[8][16];
    const int tid = threadIdx.x, wv = tid >> 6, l = tid & 63;
    const int lq = l & 15, lg = l >> 4;
    const int bid = blockIdx.x;
    const int bh = 4 * (bid & 7) + ((bid >> 3) & 3);
    const int q0 = (bid >> 5) * 16;
    const int b = bh >> 3, h = bh & 7;

    // ---- Phase 1: QK^T swapped: lane holds score[q0+lq][256wv+16it+4lg+r]
    const unsigned short* qp = q + ((size_t)bh * S + q0 + lq) * DK + 8 * lg;
    const short8v qf0 = *reinterpret_cast<const short8v*>(qp);
    const short8v qf1 = *reinterpret_cast<const short8v*>(qp + 32);
    const unsigned short* kbase = kpack + (size_t)bh * HFRAG + (size_t)l * 8;
    f32x4 acc[16];
#pragma unroll
    for (int it = 0; it < 16; ++it) {
        const unsigned short* kc = kbase + (size_t)(16 * wv + it) * 1024;
        const short8v kf0 = *reinterpret_cast<const short8v*>(kc);
        const short8v kf1 = *reinterpret_cast<const short8v*>(kc + 512);
        f32x4 a = {0.f, 0.f, 0.f, 0.f};
        a = __builtin_amdgcn_mfma_f32_16x16x32_bf16(kf0, qf0, a, 0, 0, 0);
        a = __builtin_amdgcn_mfma_f32_16x16x32_bf16(kf1, qf1, a, 0, 0, 0);
        acc[it] = a;
    }

    // ---- Phase 2: mask + row max (regs; xor16/32 cross-lane; LDS cross-wave)
    const unsigned* mrow = mbits + ((size_t)b * S + q0 + lq) * 64 + 8 * wv;
    const uint4 mwa = *reinterpret_cast<const uint4*>(mrow);
    const uint4 mwb = *reinterpret_cast<const uint4*>(mrow + 4);
    const unsigned mw[8] = {mwa.x, mwa.y, mwa.z, mwa.w, mwb.x, mwb.y, mwb.z, mwb.w};
    float vmax = -3e38f;
#pragma unroll
    for (int it = 0; it < 16; ++it) {
        const unsigned word = mw[it >> 1] >> (16 * (it & 1) + 4 * lg);
#pragma unroll
        for (int r = 0; r < 4; ++r) {
            const float v = ((word >> r) & 1u) ? -1e30f : acc[it][r];
            acc[it][r] = v;
            vmax = fmaxf(vmax, v);
        }
    }
    vmax = fmaxf(vmax, __shfl_xor(vmax, 16));
    vmax = fmaxf(vmax, __shfl_xor(vmax, 32));
    if (l < 16) redm[wv][l] = vmax;
    __syncthreads();
    float rmax = redm[0][lq];
#pragma unroll
    for (int w2 = 1; w2 < 8; ++w2) rmax = fmaxf(rmax, redm[w2][lq]);

    float sum = 0.f;
#pragma unroll
    for (int it = 0; it < 16; ++it)
#pragma unroll
        for (int r = 0; r < 4; ++r) {
            const float v = exp2f(acc[it][r] - rmax);   // scores already *log2e
            acc[it][r] = v;
            sum += v;
        }
    sum += __shfl_xor(sum, 16);
    sum += __shfl_xor(sum, 32);
    if (l < 16) reds[wv][l] = sum;
    __syncthreads();
    float rsum = 0.f;
#pragma unroll
    for (int w2 = 0; w2 < 8; ++w2) rsum += reds[w2][lq];
    const float inv = 1.0f / rsum;

    // ---- Phase 3: normalize in regs; P bf16 -> LDS only
    const int swz = (lq & 7) << 4;
    char* prow = Pc + lq * 4096;
#pragma unroll
    for (int it = 0; it < 16; ++it) {
        const int n = 16 * it + 4 * lg;
        ushort4 p;
        p.x = f2bf(acc[it][0] * inv); p.y = f2bf(acc[it][1] * inv);
        p.z = f2bf(acc[it][2] * inv); p.w = f2bf(acc[it][3] * inv);
        *reinterpret_cast<ushort4*>(prow + ((2 * (256 * wv + n)) ^ swz)) = p;
    }
    __syncthreads();

    // ---- Phase 4: PV MFMA + interleaved NT attn f32 writes (r12 path).
    const int dt = wv & 3, kh = wv >> 2;
    const int rswz = (lq & 7) << 4;
    f32x4 pacc = {0.f, 0.f, 0.f, 0.f};
    const unsigned short* vbase = vpack + (size_t)bh * HFRAG + dt * 512 + (size_t)l * 8;
    const int wrow = 8 * kh + 2 * dt + (l >> 5);         // this lane's attn row
    const int wswz = (wrow & 7) << 4;
    const int lc = l & 31;
    float* arow = attn + ((size_t)bh * S + q0 + wrow) * S;
#pragma unroll 4
    for (int s = 0; s < 32; ++s) {
        const int kk0 = kh * 1024 + 32 * s;
        const short8v a = *reinterpret_cast<const short8v*>(
            Pc + lq * 4096 + ((2 * (kk0 + 8 * lg)) ^ rswz));
        const short8v bf = *reinterpret_cast<const short8v*>(
            vbase + (size_t)(kh * 32 + s) * 2048);
        pacc = __builtin_amdgcn_mfma_f32_16x16x32_bf16(a, bf, pacc, 0, 0, 0);
        const unsigned pw = *reinterpret_cast<const unsigned*>(
            Pc + wrow * 4096 + ((128 * s + 4 * lc) ^ wswz));
        f32x2 st;
        st[0] = bf2f((unsigned short)(pw & 0xffffu));
        st[1] = bf2f((unsigned short)(pw >> 16));
        __builtin_nontemporal_store(st,
            reinterpret_cast<f32x2*>(arow + 64 * s + 2 * lc));
    }
#pragma unroll
    for (int r = 0; r < 4; ++r) cred[kh][dt][lg * 4 + r][lq] = pacc[r];
    __syncthreads();

    for (int o = tid; o < 1024; o += 512) {
        const int qq = o >> 6, dd = o & 63;
        const float val = cred[0][dd >> 4][qq][dd & 15] + cred[1][dd >> 4][qq][dd & 15];
        ctx[((size_t)(b * S + q0 + qq)) * DM + h * DK + dd] = f2bf(val);
    }
}

// ---------------------------------------------------------------------------
// Fused output projection + residual + LayerNorm.
__global__ __launch_bounds__(512)
void out_ln(const unsigned short* __restrict__ Xc, const unsigned short* __restrict__ Wt,
            const float* __restrict__ bias, const float* __restrict__ resid,
            float* __restrict__ out)
{
    __shared__ f32x2 red[32][8];
    __shared__ f32x2 stat[32];
    const int tid = threadIdx.x, wv = tid >> 6, l = tid & 63, lr = l & 31, lh = l >> 5;
    const int m0 = blockIdx.x * 32;
    const int n0 = wv * 64;
    const unsigned short* xp = Xc + (size_t)(m0 + lr) * DM + 8 * lh;
    const unsigned short* w0 = Wt + (size_t)(n0 + lr) * DM + 8 * lh;
    const unsigned short* w1 = w0 + (size_t)32 * DM;
    f32x16 acc0 = ZERO16, acc1 = ZERO16;
#pragma unroll 8
    for (int t = 0; t < 32; ++t) {
        short8v a  = *reinterpret_cast<const short8v*>(xp + 16 * t);
        short8v b0 = *reinterpret_cast<const short8v*>(w0 + 16 * t);
        short8v b1 = *reinterpret_cast<const short8v*>(w1 + 16 * t);
        acc0 = __builtin_amdgcn_mfma_f32_32x32x16_bf16(a, b0, acc0, 0, 0, 0);
        acc1 = __builtin_amdgcn_mfma_f32_32x32x16_bf16(a, b1, acc1, 0, 0, 0);
    }
    const float bv0 = bias[n0 + lr], bv1 = bias[n0 + 32 + lr];
#pragma unroll
    for (int r = 0; r < 16; ++r) {
        const int mloc = (r & 3) + 8 * (r >> 2) + 4 * lh;
        const size_t mbase = (size_t)(m0 + mloc) * DM + n0 + lr;
        const float v0 = acc0[r] + bv0 + resid[mbase];
        const float v1 = acc1[r] + bv1 + resid[mbase + 32];
        acc0[r] = v0; acc1[r] = v1;
        float s = v0 + v1, sq = v0 * v0 + v1 * v1;
#pragma unroll
        for (int off = 16; off; off >>= 1) {
            s  += __shfl_xor(s, off);
            sq += __shfl_xor(sq, off);
        }
        if (lr == 0) { f32x2 t2; t2[0] = s; t2[1] = sq; red[mloc][wv] = t2; }
    }
    __syncthreads();
    if (tid < 32) {
        float s = 0.f, sq = 0.f;
#pragma unroll
        for (int w2 = 0; w2 < 8; ++w2) { s += red[tid][w2][0]; sq += red[tid][w2][1]; }
        const float mean = s * (1.0f / 512.0f);
        const float var = sq * (1.0f / 512.0f) - mean * mean;
        f32x2 t2; t2[0] = mean; t2[1] = rsqrtf(var + 1e-5f);
        stat[tid] = t2;
    }
    __syncthreads();
#pragma unroll
    for (int r = 0; r < 16; ++r) {
        const int mloc = (r & 3) + 8 * (r >> 2) + 4 * lh;
        const f32x2 st = stat[mloc];
        const size_t mbase = (size_t)(m0 + mloc) * DM + n0 + lr;
        out[mbase]      = (acc0[r] - st[0]) * st[1];
        out[mbase + 32] = (acc1[r] - st[0]) * st[1];
    }
}

// ---------------------------------------------------------------------------
extern "C" void kernel_launch(void* const* d_in, const int* in_sizes, int n_in,
                              void* d_out, int out_size, void* d_ws, size_t ws_size,
                              hipStream_t stream)
{
    (void)in_sizes; (void)n_in; (void)out_size; (void)ws_size;

    const float*   Qin  = (const float*)d_in[0];
    const float*   Kin  = (const float*)d_in[1];
    const float*   Vin  = (const float*)d_in[2];
    const uint8_t* mask = (const uint8_t*)d_in[3];
    const float*   Wq   = (const float*)d_in[4];
    const float*   bq   = (const float*)d_in[5];
    const float*   Wk   = (const float*)d_in[6];
    const float*   bk   = (const float*)d_in[7];
    const float*   Wv   = (const float*)d_in[8];
    const float*   bv   = (const float*)d_in[9];
    const float*   Wo   = (const float*)d_in[10];
    const float*   bo   = (const float*)d_in[11];

    float* out  = (float*)d_out;
    float* attn = out + OUT_ELEMS;

    char* w = (char*)d_ws;
    const size_t MB = 1 << 20;
    unsigned short* wt    = (unsigned short*)(w);             // 2 MB (4 matrices)
    unsigned short* qbf   = (unsigned short*)(w + 2  * MB);   // 8 MB
    unsigned short* kpack = (unsigned short*)(w + 10 * MB);   // 8 MB
    unsigned short* vpack = (unsigned short*)(w + 18 * MB);   // 8 MB
    unsigned short* ctx   = (unsigned short*)(w + 26 * MB);   // 8 MB
    unsigned*       mbits = (unsigned*)(w + 34 * MB);         // 2 MB -> 36 MB

    unsigned short* wto = wt + 3 * (size_t)DM * DM;

    wconv<<<dim3(16, 16, 4), 256, 0, stream>>>(Wq, Wk, Wv, Wo, wt);

    proj3_mfma<<<dim3(DM / 64, ROWS / 128, 4), 256, 0, stream>>>(
        Qin, Kin, Vin, wt, bq, bk, bv, mask, mbits, qbf, kpack, vpack);

    attn_fused<<<4096, 512, 0, stream>>>(qbf, kpack, vpack, mbits, attn, ctx);

    out_ln<<<ROWS / 32, 512, 0, stream>>>(ctx, wto, bo, Qin, out);
}

// Round 16
// 308.812 us; speedup vs baseline: 1.0917x; 1.0235x over previous
//
#include <hip/hip_runtime.h>
#include <hip/hip_bf16.h>
#include <cstdint>
#include <cstddef>

// Round 16 = exact r12 revert (best: 309.4 us). r13 (store tail) neutral,
// r14 (QBLK32) -28us regression, r15 (exp2+merged maskpack) -7us regression.
// Pipeline: wconv -> maskpack -> proj3_mfma (MFMA, packed k/v epilogues)
// -> attn_fused (swapped-QK^T reg softmax, P in LDS, PV + interleaved NT
// attn writes, XCD-aware mapping) -> out_ln (proj + residual + LayerNorm).

typedef __attribute__((ext_vector_type(8)))  short short8v;
typedef __attribute__((ext_vector_type(2)))  float f32x2;
typedef __attribute__((ext_vector_type(4)))  float f32x4;
typedef __attribute__((ext_vector_type(16))) float f32x16;

constexpr int DM = 512, S = 2048, BATCH = 4, NHEAD = 8, DK = 64;
constexpr int ROWS = BATCH * S;                 // 8192
constexpr int BH   = BATCH * NHEAD;             // 32
constexpr size_t OUT_ELEMS = (size_t)ROWS * DM; // 4,194,304
constexpr size_t HFRAG = 131072;                // elems per bh in packed k/v

#define ZERO16 {0.f,0.f,0.f,0.f,0.f,0.f,0.f,0.f,0.f,0.f,0.f,0.f,0.f,0.f,0.f,0.f}

__device__ __forceinline__ unsigned short f2bf(float f) {
    union { __hip_bfloat16 b; unsigned short u; } c;
    c.b = __float2bfloat16(f);   // RNE
    return c.u;
}
__device__ __forceinline__ float bf2f(unsigned short u) {
    union { float f; unsigned u32; } c;
    c.u32 = (unsigned)u << 16;
    return c.f;
}

// ---------------------------------------------------------------------------
__global__ __launch_bounds__(256)
void wconv(const float* __restrict__ Wq, const float* __restrict__ Wk,
           const float* __restrict__ Wv, const float* __restrict__ Wo,
           unsigned short* __restrict__ wt)
{
    __shared__ float T[32][33];
    const float* srcs[4] = {Wq, Wk, Wv, Wo};
    const float* W = srcs[blockIdx.z];
    unsigned short* out = wt + (size_t)blockIdx.z * DM * DM;
    const int r0 = blockIdx.y * 32, c0 = blockIdx.x * 32;
    const int tid = threadIdx.x;
#pragma unroll
    for (int i = 0; i < 4; ++i) {
        int lin = tid + i * 256; int r = lin >> 5, c = lin & 31;
        T[r][c] = W[(size_t)(r0 + r) * DM + c0 + c];
    }
    __syncthreads();
#pragma unroll
    for (int i = 0; i < 4; ++i) {
        int lin = tid + i * 256; int rn = lin >> 5, ck = lin & 31;
        out[(size_t)(c0 + rn) * DM + r0 + ck] = f2bf(T[ck][rn]);
    }
}

// ---------------------------------------------------------------------------
// Pack bool mask to bits: mb[row][w] bit k <-> mask[row][32w+k]!=0.
__global__ __launch_bounds__(256)
void maskpack(const uint8_t* __restrict__ mask, unsigned* __restrict__ mb)
{
    const int t = threadIdx.x;
    const int row = blockIdx.x * 4 + (t >> 6);
    const int w = t & 63;
    const uint8_t* src = mask + (size_t)row * S + 32 * w;
    const uint4 a = *reinterpret_cast<const uint4*>(src);
    const uint4 b = *reinterpret_cast<const uint4*>(src + 16);
    const unsigned m8[8] = {a.x, a.y, a.z, a.w, b.x, b.y, b.z, b.w};
    unsigned bits = 0;
#pragma unroll
    for (int k2 = 0; k2 < 32; ++k2)
        bits |= (((m8[k2 >> 2] >> (8 * (k2 & 3))) & 0xffu) ? 1u : 0u) << k2;
    mb[(size_t)row * 64 + w] = bits;
}

// ---------------------------------------------------------------------------
// Projections. q: [bh][s][64]. k/v in fragment-packed layouts (round 4).
// Epilogue: LDS-staged coalesced stores (z=0/1), ushort4 direct (z=2).
__global__ __launch_bounds__(256)
void proj3_mfma(const float* __restrict__ Qin, const float* __restrict__ Kin,
                const float* __restrict__ Vin, const unsigned short* __restrict__ wt,
                const float* __restrict__ bq, const float* __restrict__ bk,
                const float* __restrict__ bv,
                unsigned short* __restrict__ qo, unsigned short* __restrict__ ko,
                unsigned short* __restrict__ vo)
{
    __shared__ __align__(16) char stg[16384];   // 4 waves x 4KB, wave-private
    const int z = blockIdx.z;
    const float* X = (z == 0) ? Qin : (z == 1) ? Kin : Vin;
    const unsigned short* Wt = wt + (size_t)z * DM * DM;
    const float* bias = (z == 0) ? bq : (z == 1) ? bk : bv;
    const float scale = (z == 0) ? 0.125f : 1.0f;

    const int tid = threadIdx.x, wv = tid >> 6, l = tid & 63, lr = l & 31, lh = l >> 5;
    const int m0 = blockIdx.y * 128 + wv * 32;
    const int n0 = blockIdx.x * 64;
    const float* xp = X + (size_t)(m0 + lr) * DM + 8 * lh;
    const unsigned short* w0 = Wt + (size_t)(n0 + lr) * DM + 8 * lh;
    const unsigned short* w1 = w0 + (size_t)32 * DM;
    f32x16 acc0 = ZERO16, acc1 = ZERO16;
#pragma unroll 8
    for (int t = 0; t < 32; ++t) {
        float4 xa = *reinterpret_cast<const float4*>(xp + 16 * t);
        float4 xb = *reinterpret_cast<const float4*>(xp + 16 * t + 4);
        short8v a;
        a[0] = (short)f2bf(xa.x * scale); a[1] = (short)f2bf(xa.y * scale);
        a[2] = (short)f2bf(xa.z * scale); a[3] = (short)f2bf(xa.w * scale);
        a[4] = (short)f2bf(xb.x * scale); a[5] = (short)f2bf(xb.y * scale);
        a[6] = (short)f2bf(xb.z * scale); a[7] = (short)f2bf(xb.w * scale);
        short8v b0 = *reinterpret_cast<const short8v*>(w0 + 16 * t);
        short8v b1 = *reinterpret_cast<const short8v*>(w1 + 16 * t);
        acc0 = __builtin_amdgcn_mfma_f32_32x32x16_bf16(a, b0, acc0, 0, 0, 0);
        acc1 = __builtin_amdgcn_mfma_f32_32x32x16_bf16(a, b1, acc1, 0, 0, 0);
    }

    const int h  = n0 >> 6;
    const int b  = m0 >> 11;
    const int bh = b * NHEAD + h;
    const float bv0 = bias[n0 + lr] * scale;
    const float bv1 = bias[n0 + 32 + lr] * scale;

    if (z == 2) {
        // vpack direct: r-quad -> 4 consecutive (s&7) elems -> ushort4.
        const int s32 = (m0 & (S - 1)) >> 5;
        unsigned short* vp = vo + (size_t)bh * HFRAG + (size_t)s32 * 2048;
#pragma unroll
        for (int j = 0; j < 2; ++j) {
            const f32x16 acc = j ? acc1 : acc0;
            const float bvv = j ? bv1 : bv0;
            const int d = 32 * j + lr;
            const size_t dbase = (size_t)(d >> 4) * 512;
#pragma unroll
            for (int rq = 0; rq < 4; ++rq) {
                ushort4 pk;
                pk.x = f2bf(acc[rq * 4 + 0] + bvv);
                pk.y = f2bf(acc[rq * 4 + 1] + bvv);
                pk.z = f2bf(acc[rq * 4 + 2] + bvv);
                pk.w = f2bf(acc[rq * 4 + 3] + bvv);
                const size_t idx = dbase + (size_t)(((d & 15) + 16 * rq) << 3) + 4 * lh;
                *reinterpret_cast<ushort4*>(vp + idx) = pk;
            }
        }
    } else {
        // Stage wave's 32x64 bf16 tile in LDS (swizzled), wave-private.
        char* tb = stg + wv * 4096;
#pragma unroll
        for (int j = 0; j < 2; ++j) {
            const f32x16 acc = j ? acc1 : acc0;
            const float bvv = j ? bv1 : bv0;
            const int cb = (32 * j + lr) * 2;
#pragma unroll
            for (int r = 0; r < 16; ++r) {
                const int ml = (r & 3) + 8 * (r >> 2) + 4 * lh;
                *reinterpret_cast<unsigned short*>(
                    tb + ml * 128 + (cb ^ ((ml & 7) << 4))) = f2bf(acc[r] + bvv);
            }
        }
        // Coalesced copy-out (wave-private; compiler orders via lgkmcnt).
        if (z == 0) {
            const int s0 = m0 & (S - 1);
            unsigned short* qp = qo + ((size_t)bh * S + s0) * DK;
#pragma unroll
            for (int it = 0; it < 4; ++it) {
                const int row = it * 8 + (l >> 3);
                const int cb = (l & 7) * 16;
                const short8v v = *reinterpret_cast<const short8v*>(
                    tb + row * 128 + (cb ^ ((row & 7) << 4)));
                *reinterpret_cast<short8v*>(
                    reinterpret_cast<char*>(qp + (size_t)row * DK) + cb) = v;
            }
        } else {
            const int s16 = (m0 & (S - 1)) >> 4;
            unsigned short* kp = ko + (size_t)bh * HFRAG + (size_t)s16 * 1024;
#pragma unroll
            for (int it = 0; it < 4; ++it) {
                const int sb = it >> 1, dh = it & 1;
                const int srow = sb * 16 + (l & 15);
                const int dg = l >> 4;
                const short8v v = *reinterpret_cast<const short8v*>(
                    tb + srow * 128 + ((dh * 64 + dg * 16) ^ ((srow & 7) << 4)));
                *reinterpret_cast<short8v*>(
                    kp + (size_t)sb * 1024 + dh * 512 + l * 8) = v;
            }
        }
    }
}

// ---------------------------------------------------------------------------
// Fused attention (round-9 structure, NT stores). XCD-aware bid decomposition:
// xcd = bid&7, bhl = (bid>>3)&3, tile = bid>>5; bh = 4*xcd+bhl, q0 = tile*16.
__global__ __launch_bounds__(512, 4)
void attn_fused(const unsigned short* __restrict__ q,
                const unsigned short* __restrict__ kpack,
                const unsigned short* __restrict__ vpack,
                const unsigned* __restrict__ mbits,
                float* __restrict__ attn,
                unsigned short* __restrict__ ctx)
{
    __shared__ char Pc[16 * 4096];        // 64 KB: 16 rows x 2048 bf16, swizzled
    __shared__ float cred[2][4][16][16];  // 8 KB PV cross-wave reduce
    __shared__ float redm[8][16];
    __shared__ float reds[8][16];
    const int tid = threadIdx.x, wv = tid >> 6, l = tid & 63;
    const int lq = l & 15, lg = l >> 4;
    const int bid = blockIdx.x;
    const int bh = 4 * (bid & 7) + ((bid >> 3) & 3);
    const int q0 = (bid >> 5) * 16;
    const int b = bh >> 3, h = bh & 7;

    // ---- Phase 1: QK^T swapped: lane holds score[q0+lq][256wv+16it+4lg+r]
    const unsigned short* qp = q + ((size_t)bh * S + q0 + lq) * DK + 8 * lg;
    const short8v qf0 = *reinterpret_cast<const short8v*>(qp);
    const short8v qf1 = *reinterpret_cast<const short8v*>(qp + 32);
    const unsigned short* kbase = kpack + (size_t)bh * HFRAG + (size_t)l * 8;
    f32x4 acc[16];
#pragma unroll
    for (int it = 0; it < 16; ++it) {
        const unsigned short* kc = kbase + (size_t)(16 * wv + it) * 1024;
        const short8v kf0 = *reinterpret_cast<const short8v*>(kc);
        const short8v kf1 = *reinterpret_cast<const short8v*>(kc + 512);
        f32x4 a = {0.f, 0.f, 0.f, 0.f};
        a = __builtin_amdgcn_mfma_f32_16x16x32_bf16(kf0, qf0, a, 0, 0, 0);
        a = __builtin_amdgcn_mfma_f32_16x16x32_bf16(kf1, qf1, a, 0, 0, 0);
        acc[it] = a;
    }

    // ---- Phase 2: mask + row max (regs; xor16/32 cross-lane; LDS cross-wave)
    const unsigned* mrow = mbits + ((size_t)b * S + q0 + lq) * 64 + 8 * wv;
    const uint4 mwa = *reinterpret_cast<const uint4*>(mrow);
    const uint4 mwb = *reinterpret_cast<const uint4*>(mrow + 4);
    const unsigned mw[8] = {mwa.x, mwa.y, mwa.z, mwa.w, mwb.x, mwb.y, mwb.z, mwb.w};
    float vmax = -3e38f;
#pragma unroll
    for (int it = 0; it < 16; ++it) {
        const unsigned word = mw[it >> 1] >> (16 * (it & 1) + 4 * lg);
#pragma unroll
        for (int r = 0; r < 4; ++r) {
            const float v = ((word >> r) & 1u) ? -1e30f : acc[it][r];
            acc[it][r] = v;
            vmax = fmaxf(vmax, v);
        }
    }
    vmax = fmaxf(vmax, __shfl_xor(vmax, 16));
    vmax = fmaxf(vmax, __shfl_xor(vmax, 32));
    if (l < 16) redm[wv][l] = vmax;
    __syncthreads();
    float rmax = redm[0][lq];
#pragma unroll
    for (int w2 = 1; w2 < 8; ++w2) rmax = fmaxf(rmax, redm[w2][lq]);

    float sum = 0.f;
#pragma unroll
    for (int it = 0; it < 16; ++it)
#pragma unroll
        for (int r = 0; r < 4; ++r) {
            const float v = __expf(acc[it][r] - rmax);
            acc[it][r] = v;
            sum += v;
        }
    sum += __shfl_xor(sum, 16);
    sum += __shfl_xor(sum, 32);
    if (l < 16) reds[wv][l] = sum;
    __syncthreads();
    float rsum = 0.f;
#pragma unroll
    for (int w2 = 0; w2 < 8; ++w2) rsum += reds[w2][lq];
    const float inv = 1.0f / rsum;

    // ---- Phase 3: normalize in regs; P bf16 -> LDS only (no global store)
    const int swz = (lq & 7) << 4;
    char* prow = Pc + lq * 4096;
#pragma unroll
    for (int it = 0; it < 16; ++it) {
        const int n = 16 * it + 4 * lg;
        ushort4 p;
        p.x = f2bf(acc[it][0] * inv); p.y = f2bf(acc[it][1] * inv);
        p.z = f2bf(acc[it][2] * inv); p.w = f2bf(acc[it][3] * inv);
        *reinterpret_cast<ushort4*>(prow + ((2 * (256 * wv + n)) ^ swz)) = p;
    }
    __syncthreads();

    // ---- Phase 4: PV MFMA + interleaved NT attn f32 writes.
    const int dt = wv & 3, kh = wv >> 2;
    const int rswz = (lq & 7) << 4;
    f32x4 pacc = {0.f, 0.f, 0.f, 0.f};
    const unsigned short* vbase = vpack + (size_t)bh * HFRAG + dt * 512 + (size_t)l * 8;
    const int wrow = 8 * kh + 2 * dt + (l >> 5);         // this lane's attn row
    const int wswz = (wrow & 7) << 4;
    const int lc = l & 31;
    float* arow = attn + ((size_t)bh * S + q0 + wrow) * S;
#pragma unroll 4
    for (int s = 0; s < 32; ++s) {
        const int kk0 = kh * 1024 + 32 * s;
        const short8v a = *reinterpret_cast<const short8v*>(
            Pc + lq * 4096 + ((2 * (kk0 + 8 * lg)) ^ rswz));
        const short8v bf = *reinterpret_cast<const short8v*>(
            vbase + (size_t)(kh * 32 + s) * 2048);
        pacc = __builtin_amdgcn_mfma_f32_16x16x32_bf16(a, bf, pacc, 0, 0, 0);
        // attn write: cols 64s+2lc of row wrow, values from normalized bf16 P
        const unsigned pw = *reinterpret_cast<const unsigned*>(
            Pc + wrow * 4096 + ((128 * s + 4 * lc) ^ wswz));
        f32x2 st;
        st[0] = bf2f((unsigned short)(pw & 0xffffu));
        st[1] = bf2f((unsigned short)(pw >> 16));
        __builtin_nontemporal_store(st,
            reinterpret_cast<f32x2*>(arow + 64 * s + 2 * lc));
    }
#pragma unroll
    for (int r = 0; r < 4; ++r) cred[kh][dt][lg * 4 + r][lq] = pacc[r];
    __syncthreads();

    for (int o = tid; o < 1024; o += 512) {
        const int qq = o >> 6, dd = o & 63;
        const float val = cred[0][dd >> 4][qq][dd & 15] + cred[1][dd >> 4][qq][dd & 15];
        ctx[((size_t)(b * S + q0 + qq)) * DM + h * DK + dd] = f2bf(val);
    }
}

// ---------------------------------------------------------------------------
// Fused output projection + residual + LayerNorm.
__global__ __launch_bounds__(512)
void out_ln(const unsigned short* __restrict__ Xc, const unsigned short* __restrict__ Wt,
            const float* __restrict__ bias, const float* __restrict__ resid,
            float* __restrict__ out)
{
    __shared__ f32x2 red[32][8];
    __shared__ f32x2 stat[32];
    const int tid = threadIdx.x, wv = tid >> 6, l = tid & 63, lr = l & 31, lh = l >> 5;
    const int m0 = blockIdx.x * 32;
    const int n0 = wv * 64;
    const unsigned short* xp = Xc + (size_t)(m0 + lr) * DM + 8 * lh;
    const unsigned short* w0 = Wt + (size_t)(n0 + lr) * DM + 8 * lh;
    const unsigned short* w1 = w0 + (size_t)32 * DM;
    f32x16 acc0 = ZERO16, acc1 = ZERO16;
#pragma unroll 8
    for (int t = 0; t < 32; ++t) {
        short8v a  = *reinterpret_cast<const short8v*>(xp + 16 * t);
        short8v b0 = *reinterpret_cast<const short8v*>(w0 + 16 * t);
        short8v b1 = *reinterpret_cast<const short8v*>(w1 + 16 * t);
        acc0 = __builtin_amdgcn_mfma_f32_32x32x16_bf16(a, b0, acc0, 0, 0, 0);
        acc1 = __builtin_amdgcn_mfma_f32_32x32x16_bf16(a, b1, acc1, 0, 0, 0);
    }
    const float bv0 = bias[n0 + lr], bv1 = bias[n0 + 32 + lr];
#pragma unroll
    for (int r = 0; r < 16; ++r) {
        const int mloc = (r & 3) + 8 * (r >> 2) + 4 * lh;
        const size_t mbase = (size_t)(m0 + mloc) * DM + n0 + lr;
        const float v0 = acc0[r] + bv0 + resid[mbase];
        const float v1 = acc1[r] + bv1 + resid[mbase + 32];
        acc0[r] = v0; acc1[r] = v1;
        float s = v0 + v1, sq = v0 * v0 + v1 * v1;
#pragma unroll
        for (int off = 16; off; off >>= 1) {
            s  += __shfl_xor(s, off);
            sq += __shfl_xor(sq, off);
        }
        if (lr == 0) { f32x2 t2; t2[0] = s; t2[1] = sq; red[mloc][wv] = t2; }
    }
    __syncthreads();
    if (tid < 32) {
        float s = 0.f, sq = 0.f;
#pragma unroll
        for (int w2 = 0; w2 < 8; ++w2) { s += red[tid][w2][0]; sq += red[tid][w2][1]; }
        const float mean = s * (1.0f / 512.0f);
        const float var = sq * (1.0f / 512.0f) - mean * mean;
        f32x2 t2; t2[0] = mean; t2[1] = rsqrtf(var + 1e-5f);
        stat[tid] = t2;
    }
    __syncthreads();
#pragma unroll
    for (int r = 0; r < 16; ++r) {
        const int mloc = (r & 3) + 8 * (r >> 2) + 4 * lh;
        const f32x2 st = stat[mloc];
        const size_t mbase = (size_t)(m0 + mloc) * DM + n0 + lr;
        out[mbase]      = (acc0[r] - st[0]) * st[1];
        out[mbase + 32] = (acc1[r] - st[0]) * st[1];
    }
}

// ---------------------------------------------------------------------------
extern "C" void kernel_launch(void* const* d_in, const int* in_sizes, int n_in,
                              void* d_out, int out_size, void* d_ws, size_t ws_size,
                              hipStream_t stream)
{
    (void)in_sizes; (void)n_in; (void)out_size; (void)ws_size;

    const float*   Qin  = (const float*)d_in[0];
    const float*   Kin  = (const float*)d_in[1];
    const float*   Vin  = (const float*)d_in[2];
    const uint8_t* mask = (const uint8_t*)d_in[3];
    const float*   Wq   = (const float*)d_in[4];
    const float*   bq   = (const float*)d_in[5];
    const float*   Wk   = (const float*)d_in[6];
    const float*   bk   = (const float*)d_in[7];
    const float*   Wv   = (const float*)d_in[8];
    const float*   bv   = (const float*)d_in[9];
    const float*   Wo   = (const float*)d_in[10];
    const float*   bo   = (const float*)d_in[11];

    float* out  = (float*)d_out;
    float* attn = out + OUT_ELEMS;

    char* w = (char*)d_ws;
    const size_t MB = 1 << 20;
    unsigned short* wt    = (unsigned short*)(w);             // 2 MB (4 matrices)
    unsigned short* qbf   = (unsigned short*)(w + 2  * MB);   // 8 MB
    unsigned short* kpack = (unsigned short*)(w + 10 * MB);   // 8 MB
    unsigned short* vpack = (unsigned short*)(w + 18 * MB);   // 8 MB
    unsigned short* ctx   = (unsigned short*)(w + 26 * MB);   // 8 MB
    unsigned*       mbits = (unsigned*)(w + 34 * MB);         // 2 MB -> 36 MB

    unsigned short* wto = wt + 3 * (size_t)DM * DM;

    wconv<<<dim3(16, 16, 4), 256, 0, stream>>>(Wq, Wk, Wv, Wo, wt);

    maskpack<<<ROWS / 4, 256, 0, stream>>>(mask, mbits);

    proj3_mfma<<<dim3(DM / 64, ROWS / 128, 3), 256, 0, stream>>>(
        Qin, Kin, Vin, wt, bq, bk, bv, qbf, kpack, vpack);

    attn_fused<<<4096, 512, 0, stream>>>(qbf, kpack, vpack, mbits, attn, ctx);

    out_ln<<<ROWS / 32, 512, 0, stream>>>(ctx, wto, bo, Qin, out);
}